// Round 4
// baseline (221.472 us; speedup 1.0000x reference)
//
#include <hip/hip_runtime.h>

#define N_PTS 8192
#define BATCH 2
#define KNN 8
#define STILE 1024     // smoothness LDS tile (points), 16 KiB as float4
#define SUBS 32        // sub-threads per point
#define PPB 8          // points per block (256 threads)
#define CH_R 2         // chamfer rows per thread
#define CH_SLICE 256   // chamfer candidates per block

// ---------------- helpers ----------------
__device__ __forceinline__ void ce(unsigned &x, unsigned &y) {
    unsigned lo = min(x, y), hi = max(x, y); x = lo; y = hi;
}

// branchless sorted insert into ascending 8-list (15 min/max)
__device__ __forceinline__ void insert8(unsigned o[8], unsigned key) {
    unsigned n0 = min(o[0], key);
    unsigned n1 = max(o[0], min(o[1], key));
    unsigned n2 = max(o[1], min(o[2], key));
    unsigned n3 = max(o[2], min(o[3], key));
    unsigned n4 = max(o[3], min(o[4], key));
    unsigned n5 = max(o[4], min(o[5], key));
    unsigned n6 = max(o[5], min(o[6], key));
    unsigned n7 = max(o[6], min(o[7], key));
    o[0]=n0;o[1]=n1;o[2]=n2;o[3]=n3;o[4]=n4;o[5]=n5;o[6]=n6;o[7]=n7;
}

// butterfly merge stage: merge my sorted-8 with lane^d's sorted-8, keep lowest 8.
__device__ __forceinline__ void merge_stage(unsigned o[8], int d) {
    unsigned p[8], c[8];
    #pragma unroll
    for (int k = 0; k < 8; ++k) p[k] = __shfl_xor(o[k], d, 64);
    #pragma unroll
    for (int k = 0; k < 8; ++k) c[k] = min(o[k], p[7-k]);
    ce(c[0],c[4]); ce(c[1],c[5]); ce(c[2],c[6]); ce(c[3],c[7]);
    ce(c[0],c[2]); ce(c[1],c[3]); ce(c[4],c[6]); ce(c[5],c[7]);
    ce(c[0],c[1]); ce(c[2],c[3]); ce(c[4],c[5]); ce(c[6],c[7]);
    #pragma unroll
    for (int k = 0; k < 8; ++k) o[k] = c[k];
}

// ---------------- init ----------------
__global__ void init_kernel(unsigned int* __restrict__ mins, float* __restrict__ out, int n) {
    int i = blockIdx.x * blockDim.x + threadIdx.x;
    if (i < n) mins[i] = 0x7F800000u;  // +inf
    if (i == 0) out[0] = 0.0f;
}

// ---------------- chamfer: both directions, 2 rows/thread, 8 blocks/CU ----------------
__global__ __launch_bounds__(256, 8) void chamfer_min_kernel(const float* __restrict__ pc1,
                                                             const float* __restrict__ pc2,
                                                             const float* __restrict__ flow,
                                                             unsigned* __restrict__ mins) {
    const int z = blockIdx.z;
    const int b = z & 1, dir = z >> 1;
    const int tid = threadIdx.x;
    const float* base1 = pc1 + (size_t)b * N_PTS * 3;
    const float* base2 = pc2 + (size_t)b * N_PTS * 3;
    const float* fl    = flow + (size_t)b * N_PTS * 3;

    __shared__ float  sraw[CH_SLICE * 3];  // 3 KiB
    __shared__ float4 sq[CH_SLICE];        // 4 KiB: (qx,qy,qz,|q|^2)
    const int m0 = blockIdx.y * CH_SLICE;

    if (tid < CH_SLICE * 3 / 4) {
        float4 v;
        if (dir == 0) {
            v = ((const float4*)(base2 + (size_t)m0 * 3))[tid];
        } else {
            float4 a = ((const float4*)(base1 + (size_t)m0 * 3))[tid];
            float4 f = ((const float4*)(fl    + (size_t)m0 * 3))[tid];
            v = make_float4(a.x + f.x, a.y + f.y, a.z + f.z, a.w + f.w);
        }
        ((float4*)sraw)[tid] = v;
    }

    const int i0 = blockIdx.x * (256 * CH_R) + tid * CH_R;
    float mx[CH_R], my_[CH_R], mz_[CH_R], p2[CH_R], best[CH_R];
    #pragma unroll
    for (int r = 0; r < CH_R; ++r) {
        int row = i0 + r;
        float px, py, pz;
        if (dir == 0) {
            px = base1[row*3+0] + fl[row*3+0];
            py = base1[row*3+1] + fl[row*3+1];
            pz = base1[row*3+2] + fl[row*3+2];
        } else {
            px = base2[row*3+0]; py = base2[row*3+1]; pz = base2[row*3+2];
        }
        mx[r] = -2.0f * px; my_[r] = -2.0f * py; mz_[r] = -2.0f * pz;
        p2[r] = fmaf(px, px, fmaf(py, py, pz * pz));
        best[r] = __builtin_inff();
    }
    __syncthreads();
    {
        float qx = sraw[tid*3+0], qy = sraw[tid*3+1], qz = sraw[tid*3+2];
        sq[tid] = make_float4(qx, qy, qz, fmaf(qx, qx, fmaf(qy, qy, qz * qz)));
    }
    __syncthreads();

    #pragma unroll 8
    for (int jj = 0; jj < CH_SLICE; ++jj) {
        float4 q = sq[jj];
        #pragma unroll
        for (int r = 0; r < CH_R; ++r) {
            float s = fmaf(mx[r], q.x, fmaf(my_[r], q.y, fmaf(mz_[r], q.z, q.w)));
            best[r] = fminf(best[r], s);
        }
    }
    #pragma unroll
    for (int r = 0; r < CH_R; ++r) {
        float d2 = fmaxf(best[r] + p2[r], 0.0f);
        atomicMin(&mins[((size_t)dir * BATCH + b) * N_PTS + i0 + r], __float_as_uint(d2));
    }
}

// ---------------- chamfer reduce ----------------
__global__ void chamfer_reduce_kernel(const unsigned int* __restrict__ mins,
                                      float* __restrict__ out) {
    int i = blockIdx.x * 256 + threadIdx.x;
    float v = sqrtf(__uint_as_float(mins[i])) * (1.0f / (float)(BATCH * N_PTS));
    #pragma unroll
    for (int off = 32; off > 0; off >>= 1) v += __shfl_down(v, off, 64);
    __shared__ float wsum[4];
    int wid = threadIdx.x >> 6;
    if ((threadIdx.x & 63) == 0) wsum[wid] = v;
    __syncthreads();
    if (threadIdx.x == 0) {
        atomicAdd(out, wsum[0] + wsum[1] + wsum[2] + wsum[3]);
    }
}

// ---------------- smoothness: kNN-8, float-gated, 8 blocks/CU ----------------
// 256 threads = 8 points x 32 subs. Gate: s <= thr_up - |p|^2 off the 3-fma chain.
__global__ __launch_bounds__(256, 8) void smooth_kernel(const float* __restrict__ pc1,
                                                        const float* __restrict__ flow,
                                                        float* __restrict__ out) {
    const int b = blockIdx.y;
    const int tid = threadIdx.x;
    const int sub = tid & (SUBS - 1);
    const int p_local = tid >> 5;            // 0..7
    const int base_i = blockIdx.x * PPB;
    const int i = base_i + p_local;
    const float* P = pc1  + (size_t)b * N_PTS * 3;
    const float* F = flow + (size_t)b * N_PTS * 3;

    const float px = P[i*3+0], py = P[i*3+1], pz = P[i*3+2];
    const float mx = -2.0f * px, my = -2.0f * py, mz = -2.0f * pz;
    const float p2 = fmaf(px, px, fmaf(py, py, pz * pz));

    unsigned o[8];
    #pragma unroll
    for (int k = 0; k < 8; ++k) o[k] = 0xFFFFFFFFu;
    float gate_rhs = __builtin_inff();

    __shared__ float4 sq[STILE];  // 16 KiB

    #pragma unroll 1
    for (int tile = 0; tile < N_PTS / STILE; ++tile) {   // 8 tiles
        const int t0 = tile * STILE;
        __syncthreads();
        #pragma unroll
        for (int u = tid; u < STILE; u += 256) {
            int g = t0 + u;
            float qx = P[g*3+0], qy = P[g*3+1], qz = P[g*3+2];
            sq[u] = make_float4(qx, qy, qz, fmaf(qx, qx, fmaf(qy, qy, qz * qz)));
        }
        __syncthreads();
        const bool self_here = (i >= t0) && (i < t0 + STILE);
        if (tile == 0) {
            // sample pass: unconditional insert
            #pragma unroll 4
            for (int jj = sub; jj < STILE; jj += SUBS) {
                float4 q = sq[jj];
                float s = fmaf(mx, q.x, fmaf(my, q.y, fmaf(mz, q.z, q.w)));
                float d2 = fmaxf(s + p2, 0.0f);
                unsigned key = (__float_as_uint(d2) & 0xFFFFE000u) | (unsigned)jj;
                if (self_here && jj == i) key = 0xFFFFFFFFu;
                insert8(o, key);
            }
        } else {
            // gated pass: compare hangs off the 3-fma chain only
            #pragma unroll 4
            for (int jj = sub; jj < STILE; jj += SUBS) {
                float4 q = sq[jj];
                float s = fmaf(mx, q.x, fmaf(my, q.y, fmaf(mz, q.z, q.w)));
                if (__any(s <= gate_rhs)) {
                    float d2 = fmaxf(s + p2, 0.0f);
                    int j = t0 + jj;
                    unsigned key = (__float_as_uint(d2) & 0xFFFFE000u) | (unsigned)j;
                    if (self_here && j == i) key = 0xFFFFFFFFu;
                    insert8(o, key);
                }
            }
        }
        if (tile == 0 || tile == 1 || tile == 3) {
            // re-tighten threshold: merged top-8 across the point's 32 subs
            unsigned m[8];
            #pragma unroll
            for (int k = 0; k < 8; ++k) m[k] = o[k];
            merge_stage(m, 1); merge_stage(m, 2); merge_stage(m, 4);
            merge_stage(m, 8); merge_stage(m, 16);
            unsigned thr = m[7];
            // +2 truncation-ulps slack: float gate passes a superset of key<=thr
            float thr_up = __uint_as_float((thr & 0xFFFFE000u) + 0x4000u);
            gate_rhs = thr_up - p2;
        }
    }

    // final butterfly: all 32 lanes of a point end with identical sorted top-8
    merge_stage(o, 1); merge_stage(o, 2); merge_stage(o, 4);
    merge_stage(o, 8); merge_stage(o, 16);

    // lane handles neighbor (sub & 7); each neighbor counted 4x -> /4 in scale
    const int k = sub & 7;
    unsigned key = o[0];
    #pragma unroll
    for (int kk = 1; kk < 8; ++kk) key = (k == kk) ? o[kk] : key;
    int j = (int)(key & (N_PTS - 1));
    float fx = F[i*3+0], fy = F[i*3+1], fz = F[i*3+2];
    float dx = fx - F[j*3+0], dy = fy - F[j*3+1], dz = fz - F[j*3+2];
    float s = sqrtf(fmaf(dx, dx, fmaf(dy, dy, dz * dz)));
    #pragma unroll
    for (int d = 1; d < 64; d <<= 1) s += __shfl_xor(s, d, 64);
    if ((tid & 63) == 0) {
        // W_SMOOTH(0.5) * 1/4 (dup) / (B*N*K)
        atomicAdd(out, s * (0.125f / ((float)BATCH * N_PTS * KNN)));
    }
}

extern "C" void kernel_launch(void* const* d_in, const int* in_sizes, int n_in,
                              void* d_out, int out_size, void* d_ws, size_t ws_size,
                              hipStream_t stream) {
    const float* pc1  = (const float*)d_in[0];
    const float* pc2  = (const float*)d_in[1];
    const float* flow = (const float*)d_in[2];
    float* out = (float*)d_out;
    unsigned int* mins = (unsigned int*)d_ws;  // 2*B*N uints = 128 KiB

    init_kernel<<<dim3(128), 256, 0, stream>>>(mins, out, 2 * BATCH * N_PTS);

    dim3 gch(N_PTS / (256 * CH_R), N_PTS / CH_SLICE, 2 * BATCH);  // 16 x 32 x 4
    chamfer_min_kernel<<<gch, 256, 0, stream>>>(pc1, pc2, flow, mins);

    chamfer_reduce_kernel<<<dim3(2 * BATCH * N_PTS / 256), 256, 0, stream>>>(mins, out);

    smooth_kernel<<<dim3(N_PTS / PPB, BATCH), 256, 0, stream>>>(pc1, flow, out);
}

// Round 5
// 169.639 us; speedup vs baseline: 1.3055x; 1.3055x over previous
//
#include <hip/hip_runtime.h>

#define N_PTS 8192
#define BATCH 2
#define KNN 8
#define STILE 2048     // smoothness LDS tile (points), 32 KiB as float4
#define SUBS 16        // sub-threads per point
#define PPB 16         // points per block (256 threads)
#define CH_R 4         // chamfer rows per thread
#define CH_SLICE 256   // chamfer candidates per block
#define UF 8           // smooth prefetch depth
#define CUF 16         // chamfer prefetch depth

// ---------------- helpers ----------------
__device__ __forceinline__ void ce(unsigned &x, unsigned &y) {
    unsigned lo = min(x, y), hi = max(x, y); x = lo; y = hi;
}

// branchless sorted insert into ascending 8-list (15 min/max)
__device__ __forceinline__ void insert8(unsigned o[8], unsigned key) {
    unsigned n0 = min(o[0], key);
    unsigned n1 = max(o[0], min(o[1], key));
    unsigned n2 = max(o[1], min(o[2], key));
    unsigned n3 = max(o[2], min(o[3], key));
    unsigned n4 = max(o[3], min(o[4], key));
    unsigned n5 = max(o[4], min(o[5], key));
    unsigned n6 = max(o[5], min(o[6], key));
    unsigned n7 = max(o[6], min(o[7], key));
    o[0]=n0;o[1]=n1;o[2]=n2;o[3]=n3;o[4]=n4;o[5]=n5;o[6]=n6;o[7]=n7;
}

// butterfly merge stage: merge my sorted-8 with lane^d's sorted-8, keep lowest 8.
__device__ __forceinline__ void merge_stage(unsigned o[8], int d) {
    unsigned p[8], c[8];
    #pragma unroll
    for (int k = 0; k < 8; ++k) p[k] = __shfl_xor(o[k], d, 64);
    #pragma unroll
    for (int k = 0; k < 8; ++k) c[k] = min(o[k], p[7-k]);
    ce(c[0],c[4]); ce(c[1],c[5]); ce(c[2],c[6]); ce(c[3],c[7]);
    ce(c[0],c[2]); ce(c[1],c[3]); ce(c[4],c[6]); ce(c[5],c[7]);
    ce(c[0],c[1]); ce(c[2],c[3]); ce(c[4],c[5]); ce(c[6],c[7]);
    #pragma unroll
    for (int k = 0; k < 8; ++k) o[k] = c[k];
}

// ---------------- init ----------------
__global__ void init_kernel(unsigned int* __restrict__ mins, float* __restrict__ out, int n) {
    int i = blockIdx.x * blockDim.x + threadIdx.x;
    if (i < n) mins[i] = 0x7F800000u;  // +inf
    if (i == 0) out[0] = 0.0f;
}

// ---------------- chamfer: both directions, 4 rows/thread, prefetch-16 ----------------
__global__ __launch_bounds__(256, 4) void chamfer_min_kernel(const float* __restrict__ pc1,
                                                             const float* __restrict__ pc2,
                                                             const float* __restrict__ flow,
                                                             unsigned* __restrict__ mins) {
    const int z = blockIdx.z;
    const int b = z & 1, dir = z >> 1;
    const int tid = threadIdx.x;
    const float* base1 = pc1 + (size_t)b * N_PTS * 3;
    const float* base2 = pc2 + (size_t)b * N_PTS * 3;
    const float* fl    = flow + (size_t)b * N_PTS * 3;

    __shared__ float  sraw[CH_SLICE * 3];  // 3 KiB
    __shared__ float4 sq[CH_SLICE];        // 4 KiB: (qx,qy,qz,|q|^2)
    const int m0 = blockIdx.y * CH_SLICE;

    if (tid < CH_SLICE * 3 / 4) {
        float4 v;
        if (dir == 0) {
            v = ((const float4*)(base2 + (size_t)m0 * 3))[tid];
        } else {
            float4 a = ((const float4*)(base1 + (size_t)m0 * 3))[tid];
            float4 f = ((const float4*)(fl    + (size_t)m0 * 3))[tid];
            v = make_float4(a.x + f.x, a.y + f.y, a.z + f.z, a.w + f.w);
        }
        ((float4*)sraw)[tid] = v;
    }

    const int i0 = blockIdx.x * (256 * CH_R) + tid * CH_R;
    float mx[CH_R], my_[CH_R], mz_[CH_R], p2[CH_R], best[CH_R];
    #pragma unroll
    for (int r = 0; r < CH_R; ++r) {
        int row = i0 + r;
        float px, py, pz;
        if (dir == 0) {
            px = base1[row*3+0] + fl[row*3+0];
            py = base1[row*3+1] + fl[row*3+1];
            pz = base1[row*3+2] + fl[row*3+2];
        } else {
            px = base2[row*3+0]; py = base2[row*3+1]; pz = base2[row*3+2];
        }
        mx[r] = -2.0f * px; my_[r] = -2.0f * py; mz_[r] = -2.0f * pz;
        p2[r] = fmaf(px, px, fmaf(py, py, pz * pz));
        best[r] = __builtin_inff();
    }
    __syncthreads();
    {
        float qx = sraw[tid*3+0], qy = sraw[tid*3+1], qz = sraw[tid*3+2];
        sq[tid] = make_float4(qx, qy, qz, fmaf(qx, qx, fmaf(qy, qy, qz * qz)));
    }
    __syncthreads();

    #pragma unroll 1
    for (int g = 0; g < CH_SLICE; g += CUF) {
        float4 q[CUF];
        #pragma unroll
        for (int u = 0; u < CUF; ++u) q[u] = sq[g + u];  // 16 broadcast b128s in flight
        #pragma unroll
        for (int u = 0; u < CUF; ++u) {
            #pragma unroll
            for (int r = 0; r < CH_R; ++r) {
                float s = fmaf(mx[r], q[u].x, fmaf(my_[r], q[u].y, fmaf(mz_[r], q[u].z, q[u].w)));
                best[r] = fminf(best[r], s);
            }
        }
    }
    #pragma unroll
    for (int r = 0; r < CH_R; ++r) {
        float d2 = fmaxf(best[r] + p2[r], 0.0f);
        atomicMin(&mins[((size_t)dir * BATCH + b) * N_PTS + i0 + r], __float_as_uint(d2));
    }
}

// ---------------- chamfer reduce ----------------
__global__ void chamfer_reduce_kernel(const unsigned int* __restrict__ mins,
                                      float* __restrict__ out) {
    int i = blockIdx.x * 256 + threadIdx.x;
    float v = sqrtf(__uint_as_float(mins[i])) * (1.0f / (float)(BATCH * N_PTS));
    #pragma unroll
    for (int off = 32; off > 0; off >>= 1) v += __shfl_down(v, off, 64);
    __shared__ float wsum[4];
    int wid = threadIdx.x >> 6;
    if ((threadIdx.x & 63) == 0) wsum[wid] = v;
    __syncthreads();
    if (threadIdx.x == 0) {
        atomicAdd(out, wsum[0] + wsum[1] + wsum[2] + wsum[3]);
    }
}

// ---------------- smoothness: kNN-8, gated, software-pipelined ----------------
// 256 threads = 16 points x 16 subs; wave = 4 points x 16 subs.
__global__ __launch_bounds__(256, 4) void smooth_kernel(const float* __restrict__ pc1,
                                                        const float* __restrict__ flow,
                                                        float* __restrict__ out) {
    const int b = blockIdx.y;
    const int tid = threadIdx.x;
    const int sub = tid & (SUBS - 1);
    const int p_local = tid >> 4;             // 0..15
    const int i = blockIdx.x * PPB + p_local;
    const float* P = pc1  + (size_t)b * N_PTS * 3;
    const float* F = flow + (size_t)b * N_PTS * 3;

    const float px = P[i*3+0], py = P[i*3+1], pz = P[i*3+2];
    const float mx = -2.0f * px, my = -2.0f * py, mz = -2.0f * pz;
    const float p2 = fmaf(px, px, fmaf(py, py, pz * pz));

    unsigned o[8];
    #pragma unroll
    for (int k = 0; k < 8; ++k) o[k] = 0xFFFFFFFFu;
    float gate_rhs = __builtin_inff();

    __shared__ float4 sq[STILE];  // 32 KiB

    constexpr int NSTEP = STILE / SUBS;  // 128 steps per tile
    constexpr int NG = NSTEP / UF;       // 16 groups

    #pragma unroll 1
    for (int tile = 0; tile < N_PTS / STILE; ++tile) {   // 4 tiles
        const int t0 = tile * STILE;
        __syncthreads();
        #pragma unroll
        for (int u = tid; u < STILE; u += 256) {
            int g = t0 + u;
            float qx = P[g*3+0], qy = P[g*3+1], qz = P[g*3+2];
            sq[u] = make_float4(qx, qy, qz, fmaf(qx, qx, fmaf(qy, qy, qz * qz)));
        }
        __syncthreads();

        if (tile == 0) {
            // sample pass: unconditional insert, prefetch-8 pipeline
            float4 q[UF], qn[UF];
            #pragma unroll
            for (int u = 0; u < UF; ++u) q[u] = sq[sub + u * SUBS];
            #pragma unroll 2
            for (int g = 0; g < NG; ++g) {
                const int nb = (g + 1 < NG) ? (g + 1) * UF : 0;
                #pragma unroll
                for (int u = 0; u < UF; ++u) qn[u] = sq[sub + (nb + u) * SUBS];
                #pragma unroll
                for (int u = 0; u < UF; ++u) {
                    int jj = sub + (g * UF + u) * SUBS;
                    float s = fmaf(mx, q[u].x, fmaf(my, q[u].y, fmaf(mz, q[u].z, q[u].w)));
                    float d2 = fmaxf(s + p2, 0.0f);
                    unsigned key = (__float_as_uint(d2) & 0xFFFFE000u) | (unsigned)jj;
                    if (jj == i) key = 0xFFFFFFFFu;
                    insert8(o, key);
                }
                #pragma unroll
                for (int u = 0; u < UF; ++u) q[u] = qn[u];
            }
        } else {
            // gated pass: compare hangs off 3-fma chain on prefetched q
            float4 q[UF], qn[UF];
            #pragma unroll
            for (int u = 0; u < UF; ++u) q[u] = sq[sub + u * SUBS];
            #pragma unroll 2
            for (int g = 0; g < NG; ++g) {
                const int nb = (g + 1 < NG) ? (g + 1) * UF : 0;
                #pragma unroll
                for (int u = 0; u < UF; ++u) qn[u] = sq[sub + (nb + u) * SUBS];
                #pragma unroll
                for (int u = 0; u < UF; ++u) {
                    float s = fmaf(mx, q[u].x, fmaf(my, q[u].y, fmaf(mz, q[u].z, q[u].w)));
                    if (__any(s <= gate_rhs)) {
                        int j = t0 + sub + (g * UF + u) * SUBS;
                        float d2 = fmaxf(s + p2, 0.0f);
                        unsigned key = (__float_as_uint(d2) & 0xFFFFE000u) | (unsigned)j;
                        if (j == i) key = 0xFFFFFFFFu;
                        insert8(o, key);
                    }
                }
                #pragma unroll
                for (int u = 0; u < UF; ++u) q[u] = qn[u];
            }
        }

        if (tile <= 2) {
            // re-tighten threshold: merged top-8 across the point's 16 subs
            unsigned m[8];
            #pragma unroll
            for (int k = 0; k < 8; ++k) m[k] = o[k];
            merge_stage(m, 1); merge_stage(m, 2); merge_stage(m, 4); merge_stage(m, 8);
            unsigned thr = m[7];
            // +2 truncation-ulps slack: float gate passes a superset of key<=thr
            float thr_up = __uint_as_float((thr & 0xFFFFE000u) + 0x4000u);
            gate_rhs = thr_up - p2;
        }
    }

    // final butterfly: all 16 lanes of a point end with identical sorted top-8
    merge_stage(o, 1); merge_stage(o, 2); merge_stage(o, 4); merge_stage(o, 8);

    // lane handles neighbor (sub & 7); each neighbor counted 2x -> /2 in scale
    const int k = sub & 7;
    unsigned key = o[0];
    #pragma unroll
    for (int kk = 1; kk < 8; ++kk) key = (k == kk) ? o[kk] : key;
    int j = (int)(key & (N_PTS - 1));
    float fx = F[i*3+0], fy = F[i*3+1], fz = F[i*3+2];
    float dx = fx - F[j*3+0], dy = fy - F[j*3+1], dz = fz - F[j*3+2];
    float s = sqrtf(fmaf(dx, dx, fmaf(dy, dy, dz * dz)));
    #pragma unroll
    for (int d = 1; d < 64; d <<= 1) s += __shfl_xor(s, d, 64);
    if ((tid & 63) == 0) {
        // W_SMOOTH(0.5) * 1/2 (dup) / (B*N*K)
        atomicAdd(out, s * (0.25f / ((float)BATCH * N_PTS * KNN)));
    }
}

extern "C" void kernel_launch(void* const* d_in, const int* in_sizes, int n_in,
                              void* d_out, int out_size, void* d_ws, size_t ws_size,
                              hipStream_t stream) {
    const float* pc1  = (const float*)d_in[0];
    const float* pc2  = (const float*)d_in[1];
    const float* flow = (const float*)d_in[2];
    float* out = (float*)d_out;
    unsigned int* mins = (unsigned int*)d_ws;  // 2*B*N uints = 128 KiB

    init_kernel<<<dim3(128), 256, 0, stream>>>(mins, out, 2 * BATCH * N_PTS);

    dim3 gch(N_PTS / (256 * CH_R), N_PTS / CH_SLICE, 2 * BATCH);  // 8 x 32 x 4
    chamfer_min_kernel<<<gch, 256, 0, stream>>>(pc1, pc2, flow, mins);

    chamfer_reduce_kernel<<<dim3(2 * BATCH * N_PTS / 256), 256, 0, stream>>>(mins, out);

    smooth_kernel<<<dim3(N_PTS / PPB, BATCH), 256, 0, stream>>>(pc1, flow, out);
}

// Round 6
// 161.127 us; speedup vs baseline: 1.3745x; 1.0528x over previous
//
#include <hip/hip_runtime.h>

#define N_PTS 8192
#define BATCH 2
#define KNN 8
#define STILE 2048     // smoothness LDS tile (points), 32 KiB as float4
#define PPB 16         // smooth points per block (4 waves x 4 points)
#define CH_R 8         // chamfer rows per thread
#define CH_SLICE 256   // chamfer candidates per block

// ---------------- helpers ----------------
__device__ __forceinline__ void ce(unsigned &x, unsigned &y) {
    unsigned lo = min(x, y), hi = max(x, y); x = lo; y = hi;
}

// branchless sorted insert into ascending 4-list (7 min/max)
__device__ __forceinline__ void insert4(unsigned o[4], unsigned key) {
    unsigned n0 = min(o[0], key);
    unsigned n1 = max(o[0], min(o[1], key));
    unsigned n2 = max(o[1], min(o[2], key));
    unsigned n3 = max(o[2], min(o[3], key));
    o[0]=n0; o[1]=n1; o[2]=n2; o[3]=n3;
}

// butterfly merge stage on sorted-8 lists (keep lowest 8 of mine and lane^d's)
__device__ __forceinline__ void merge_stage8(unsigned m[8], int d) {
    unsigned p[8], c[8];
    #pragma unroll
    for (int k = 0; k < 8; ++k) p[k] = __shfl_xor(m[k], d, 64);
    #pragma unroll
    for (int k = 0; k < 8; ++k) c[k] = min(m[k], p[7-k]);
    ce(c[0],c[4]); ce(c[1],c[5]); ce(c[2],c[6]); ce(c[3],c[7]);
    ce(c[0],c[2]); ce(c[1],c[3]); ce(c[4],c[6]); ce(c[5],c[7]);
    ce(c[0],c[1]); ce(c[2],c[3]); ce(c[4],c[5]); ce(c[6],c[7]);
    #pragma unroll
    for (int k = 0; k < 8; ++k) m[k] = c[k];
}

// full 64-lane merge: every lane ends with the global lowest-8, sorted
__device__ __forceinline__ void merge64(unsigned m[8]) {
    merge_stage8(m, 1); merge_stage8(m, 2); merge_stage8(m, 4);
    merge_stage8(m, 8); merge_stage8(m, 16); merge_stage8(m, 32);
}

// ---------------- init ----------------
__global__ void init_kernel(unsigned int* __restrict__ mins, float* __restrict__ out, int n) {
    int i = blockIdx.x * blockDim.x + threadIdx.x;
    if (i < n) mins[i] = 0x7F800000u;  // +inf
    if (i == 0) out[0] = 0.0f;
}

// ---------------- chamfer: both directions, 8 rows/thread, prefetch-8 ----------------
__global__ __launch_bounds__(256, 4) void chamfer_min_kernel(const float* __restrict__ pc1,
                                                             const float* __restrict__ pc2,
                                                             const float* __restrict__ flow,
                                                             unsigned* __restrict__ mins) {
    const int z = blockIdx.z;
    const int b = z & 1, dir = z >> 1;
    const int tid = threadIdx.x;
    const float* base1 = pc1 + (size_t)b * N_PTS * 3;
    const float* base2 = pc2 + (size_t)b * N_PTS * 3;
    const float* fl    = flow + (size_t)b * N_PTS * 3;

    __shared__ float  sraw[CH_SLICE * 3];  // 3 KiB
    __shared__ float4 sq[CH_SLICE];        // 4 KiB: (qx,qy,qz,|q|^2)
    const int m0 = blockIdx.y * CH_SLICE;

    if (tid < CH_SLICE * 3 / 4) {
        float4 v;
        if (dir == 0) {
            v = ((const float4*)(base2 + (size_t)m0 * 3))[tid];
        } else {
            float4 a = ((const float4*)(base1 + (size_t)m0 * 3))[tid];
            float4 f = ((const float4*)(fl    + (size_t)m0 * 3))[tid];
            v = make_float4(a.x + f.x, a.y + f.y, a.z + f.z, a.w + f.w);
        }
        ((float4*)sraw)[tid] = v;
    }

    const int i0 = blockIdx.x * (256 * CH_R) + tid * CH_R;
    float mx[CH_R], my_[CH_R], mz_[CH_R], p2[CH_R], best[CH_R];
    #pragma unroll
    for (int r = 0; r < CH_R; ++r) {
        int row = i0 + r;
        float px, py, pz;
        if (dir == 0) {
            px = base1[row*3+0] + fl[row*3+0];
            py = base1[row*3+1] + fl[row*3+1];
            pz = base1[row*3+2] + fl[row*3+2];
        } else {
            px = base2[row*3+0]; py = base2[row*3+1]; pz = base2[row*3+2];
        }
        mx[r] = -2.0f * px; my_[r] = -2.0f * py; mz_[r] = -2.0f * pz;
        p2[r] = fmaf(px, px, fmaf(py, py, pz * pz));
        best[r] = __builtin_inff();
    }
    __syncthreads();
    {
        float qx = sraw[tid*3+0], qy = sraw[tid*3+1], qz = sraw[tid*3+2];
        sq[tid] = make_float4(qx, qy, qz, fmaf(qx, qx, fmaf(qy, qy, qz * qz)));
    }
    __syncthreads();

    #pragma unroll 1
    for (int g = 0; g < CH_SLICE; g += 8) {
        float4 q[8];
        #pragma unroll
        for (int u = 0; u < 8; ++u) q[u] = sq[g + u];
        #pragma unroll
        for (int u = 0; u < 8; ++u) {
            #pragma unroll
            for (int r = 0; r < CH_R; ++r) {
                float s = fmaf(mx[r], q[u].x, fmaf(my_[r], q[u].y, fmaf(mz_[r], q[u].z, q[u].w)));
                best[r] = fminf(best[r], s);
            }
        }
    }
    #pragma unroll
    for (int r = 0; r < CH_R; ++r) {
        float d2 = fmaxf(best[r] + p2[r], 0.0f);
        atomicMin(&mins[((size_t)dir * BATCH + b) * N_PTS + i0 + r], __float_as_uint(d2));
    }
}

// ---------------- chamfer reduce ----------------
__global__ void chamfer_reduce_kernel(const unsigned int* __restrict__ mins,
                                      float* __restrict__ out) {
    int i = blockIdx.x * 256 + threadIdx.x;
    float v = sqrtf(__uint_as_float(mins[i])) * (1.0f / (float)(BATCH * N_PTS));
    #pragma unroll
    for (int off = 32; off > 0; off >>= 1) v += __shfl_down(v, off, 64);
    __shared__ float wsum[4];
    int wid = threadIdx.x >> 6;
    if ((threadIdx.x & 63) == 0) wsum[wid] = v;
    __syncthreads();
    if (threadIdx.x == 0) {
        atomicAdd(out, wsum[0] + wsum[1] + wsum[2] + wsum[3]);
    }
}

// ---------------- smoothness: wave owns 4 points, lane owns candidate slice ----------------
// Per-lane top-4 per point; tile0 unconditional -> thr; tiles 1..3 gated per point.
__global__ __launch_bounds__(256, 4) void smooth_kernel(const float* __restrict__ pc1,
                                                        const float* __restrict__ flow,
                                                        float* __restrict__ out) {
    const int b = blockIdx.y;
    const int tid = threadIdx.x;
    const int wv = tid >> 6, lane = tid & 63;
    const int i0w = blockIdx.x * PPB + wv * 4;   // wave's 4 points: i0w..i0w+3
    const float* P = pc1  + (size_t)b * N_PTS * 3;
    const float* F = flow + (size_t)b * N_PTS * 3;

    float mx[4], my[4], mz[4], p2[4], gr[4];
    #pragma unroll
    for (int r = 0; r < 4; ++r) {
        int i = i0w + r;
        float px = P[i*3+0], py = P[i*3+1], pz = P[i*3+2];
        mx[r] = -2.0f * px; my[r] = -2.0f * py; mz[r] = -2.0f * pz;
        p2[r] = fmaf(px, px, fmaf(py, py, pz * pz));
        gr[r] = __builtin_inff();
    }

    unsigned o[4][4];
    #pragma unroll
    for (int r = 0; r < 4; ++r) {
        #pragma unroll
        for (int k = 0; k < 4; ++k) o[r][k] = 0xFFFFFFFFu;
    }

    __shared__ float4 sq[STILE];   // 32 KiB
    __shared__ float psum[4];

    #pragma unroll 1
    for (int tile = 0; tile < N_PTS / STILE; ++tile) {   // 4 tiles
        const int t0 = tile * STILE;
        __syncthreads();
        for (int u = tid; u < STILE; u += 256) {
            int g = t0 + u;
            float qx = P[g*3+0], qy = P[g*3+1], qz = P[g*3+2];
            sq[u] = make_float4(qx, qy, qz, fmaf(qx, qx, fmaf(qy, qy, qz * qz)));
        }
        __syncthreads();

        if (tile == 0) {
            // unconditional pass over tile0 (establishes both lists and thr)
            float4 qa = sq[lane];
            #pragma unroll 1
            for (int st = 0; st < 32; ++st) {
                float4 qb = sq[(((st + 1) & 31) * 64) + lane];  // prefetch (wraps harmlessly)
                int j = st * 64 + lane;
                #pragma unroll
                for (int r = 0; r < 4; ++r) {
                    float s = fmaf(mx[r], qa.x, fmaf(my[r], qa.y, fmaf(mz[r], qa.z, qa.w)));
                    float d2 = fmaxf(s + p2[r], 0.0f);
                    unsigned key = (__float_as_uint(d2) & 0xFFFFE000u) | (unsigned)j;
                    key = (j == i0w + r) ? 0xFFFFFFFFu : key;
                    insert4(o[r], key);
                }
                qa = qb;
            }
            // thr per point: 8th-smallest of union of lane top-4s (safe upper bound)
            #pragma unroll
            for (int r = 0; r < 4; ++r) {
                unsigned m[8] = {o[r][0], o[r][1], o[r][2], o[r][3],
                                 0xFFFFFFFFu, 0xFFFFFFFFu, 0xFFFFFFFFu, 0xFFFFFFFFu};
                merge64(m);
                // +2 truncation-buckets slack: gate passes superset of key<=thr
                float thr_up = __uint_as_float((m[7] & 0xFFFFE000u) + 0x4000u);
                gr[r] = thr_up - p2[r];
            }
        } else {
            float4 qa = sq[lane];
            #pragma unroll 1
            for (int st = 0; st < 32; ++st) {
                float4 qb = sq[(((st + 1) & 31) * 64) + lane];
                int j = t0 + st * 64 + lane;
                float s0 = fmaf(mx[0], qa.x, fmaf(my[0], qa.y, fmaf(mz[0], qa.z, qa.w)));
                float s1 = fmaf(mx[1], qa.x, fmaf(my[1], qa.y, fmaf(mz[1], qa.z, qa.w)));
                float s2 = fmaf(mx[2], qa.x, fmaf(my[2], qa.y, fmaf(mz[2], qa.z, qa.w)));
                float s3 = fmaf(mx[3], qa.x, fmaf(my[3], qa.y, fmaf(mz[3], qa.z, qa.w)));
                if (__any(s0 <= gr[0])) {
                    float d2 = fmaxf(s0 + p2[0], 0.0f);
                    unsigned key = (__float_as_uint(d2) & 0xFFFFE000u) | (unsigned)j;
                    key = (j == i0w + 0) ? 0xFFFFFFFFu : key;
                    insert4(o[0], key);
                }
                if (__any(s1 <= gr[1])) {
                    float d2 = fmaxf(s1 + p2[1], 0.0f);
                    unsigned key = (__float_as_uint(d2) & 0xFFFFE000u) | (unsigned)j;
                    key = (j == i0w + 1) ? 0xFFFFFFFFu : key;
                    insert4(o[1], key);
                }
                if (__any(s2 <= gr[2])) {
                    float d2 = fmaxf(s2 + p2[2], 0.0f);
                    unsigned key = (__float_as_uint(d2) & 0xFFFFE000u) | (unsigned)j;
                    key = (j == i0w + 2) ? 0xFFFFFFFFu : key;
                    insert4(o[2], key);
                }
                if (__any(s3 <= gr[3])) {
                    float d2 = fmaxf(s3 + p2[3], 0.0f);
                    unsigned key = (__float_as_uint(d2) & 0xFFFFE000u) | (unsigned)j;
                    key = (j == i0w + 3) ? 0xFFFFFFFFu : key;
                    insert4(o[3], key);
                }
                qa = qb;
            }
        }
    }

    // final per-point merge across all 64 lanes
    unsigned fin[4][8];
    #pragma unroll
    for (int r = 0; r < 4; ++r) {
        unsigned m[8] = {o[r][0], o[r][1], o[r][2], o[r][3],
                         0xFFFFFFFFu, 0xFFFFFFFFu, 0xFFFFFFFFu, 0xFFFFFFFFu};
        merge64(m);
        #pragma unroll
        for (int k = 0; k < 8; ++k) fin[r][k] = m[k];
    }

    // lanes 0..31 cover (point r = lane>>3, neighbor k = lane&7); 32..63 duplicate (x2)
    const int sel = lane & 31;
    unsigned key = fin[0][0];
    #pragma unroll
    for (int rr = 0; rr < 4; ++rr) {
        #pragma unroll
        for (int kk = 0; kk < 8; ++kk) {
            if (sel == rr * 8 + kk) key = fin[rr][kk];
        }
    }
    const int r = sel >> 3;
    const int i = i0w + r;
    const int j = (int)(key & (N_PTS - 1));
    float dx = F[i*3+0] - F[j*3+0];
    float dy = F[i*3+1] - F[j*3+1];
    float dz = F[i*3+2] - F[j*3+2];
    float s = sqrtf(fmaf(dx, dx, fmaf(dy, dy, dz * dz)));
    #pragma unroll
    for (int d = 1; d < 64; d <<= 1) s += __shfl_xor(s, d, 64);
    if (lane == 0) psum[wv] = s;
    __syncthreads();
    if (tid == 0) {
        // W_SMOOTH(0.5) * 1/2 (lane duplication) / (B*N*K)
        atomicAdd(out, (psum[0] + psum[1] + psum[2] + psum[3]) *
                       (0.25f / ((float)BATCH * N_PTS * KNN)));
    }
}

extern "C" void kernel_launch(void* const* d_in, const int* in_sizes, int n_in,
                              void* d_out, int out_size, void* d_ws, size_t ws_size,
                              hipStream_t stream) {
    const float* pc1  = (const float*)d_in[0];
    const float* pc2  = (const float*)d_in[1];
    const float* flow = (const float*)d_in[2];
    float* out = (float*)d_out;
    unsigned int* mins = (unsigned int*)d_ws;  // 2*B*N uints = 128 KiB

    init_kernel<<<dim3(128), 256, 0, stream>>>(mins, out, 2 * BATCH * N_PTS);

    dim3 gch(N_PTS / (256 * CH_R), N_PTS / CH_SLICE, 2 * BATCH);  // 4 x 32 x 4
    chamfer_min_kernel<<<gch, 256, 0, stream>>>(pc1, pc2, flow, mins);

    chamfer_reduce_kernel<<<dim3(2 * BATCH * N_PTS / 256), 256, 0, stream>>>(mins, out);

    smooth_kernel<<<dim3(N_PTS / PPB, BATCH), 256, 0, stream>>>(pc1, flow, out);
}